// Round 5
// baseline (1143.860 us; speedup 1.0000x reference)
//
#include <hip/hip_runtime.h>
#include <hip/hip_cooperative_groups.h>
#include <math.h>
#include <stdint.h>

namespace cg = cooperative_groups;

constexpr int LL = 16384;
constexpr int NROW = 65536;             // N*L
constexpr int NPAIR = NROW * 8;         // 524288 (row,head) pairs
constexpr int PAIRS_PER_N = NPAIR / 4;  // 131072
constexpr float EPS = 1e-6f;
constexpr float LN_EPS = 1e-5f;

// ---------------- fused cooperative layout ----------------
constexpr int GRID = 1024;              // 4 blocks/CU x 256 CUs (cooperative)
// finals
constexpr int F_QSUM = 0;               // [4][128]
constexpr int F_KSUM = 512;             // [4][128]
constexpr int F_QN   = 1024;            // [4][128]
constexpr int F_KN   = 1536;            // [4][128]
constexpr int F_SS   = 2048;            // [4][8]
constexpr int F_KV   = 2080;            // [4][2048]
// per-block partials (no atomics, no zeroing needed — fully overwritten)
constexpr int P_A1 = 10272;             // [1024][256]  qsum|ksum
constexpr int P_A2 = P_A1 + GRID * 256; // [1024][256]  qn|kn
constexpr int P_SS = P_A2 + GRID * 256; // [1024][8]
constexpr int P_KV = P_SS + GRID * 8;   // [1024][2048]
constexpr size_t WS_FUSED = (size_t)(P_KV + GRID * 2048) * 4;  // ~10.6 MB

// ---------------- fallback (round-3 proven path) layout ----------------
constexpr int FB_QSUM = 0;
constexpr int FB_KSUM = 512;
constexpr int FB_QN   = 1024;
constexpr int FB_KN   = 1536;
constexpr int FB_SSUM = 2048;
constexpr int FB_KVU  = 2080;
constexpr int FB_STATS_FLOATS = FB_KVU + 4 * 2048;  // 10272
constexpr int FB_FLOAT_END = 10304;
constexpr size_t FB_MIR_Q_BYTE = (size_t)FB_FLOAT_END * 4;
constexpr size_t FB_MIR_ELEMS  = (size_t)NPAIR * 16;
constexpr size_t FB_MIR_K_BYTE = FB_MIR_Q_BYTE + FB_MIR_ELEMS * 2;
constexpr size_t FB_WS_FULL    = FB_MIR_K_BYTE + FB_MIR_ELEMS * 2;

__device__ __forceinline__ float sigm(float x) { return __fdividef(1.f, 1.f + __expf(-x)); }
__device__ __forceinline__ unsigned short f2bf(float f) {
  uint32_t x = __float_as_uint(f);
  return (unsigned short)((x + 0x7FFFu + ((x >> 16) & 1u)) >> 16);
}
__device__ __forceinline__ float bf2f(unsigned short u) {
  return __uint_as_float(((uint32_t)u) << 16);
}

__device__ __forceinline__ void load_sig_f32(const float* fp, int p, float* r) {
  const float4* p4 = reinterpret_cast<const float4*>(fp + (size_t)p * 16);
#pragma unroll
  for (int j = 0; j < 4; ++j) {
    float4 a = p4[j];
    r[4 * j] = sigm(a.x); r[4 * j + 1] = sigm(a.y);
    r[4 * j + 2] = sigm(a.z); r[4 * j + 3] = sigm(a.w);
  }
}
__device__ __forceinline__ void load_raw16(const float* fp, int p, float* r) {
  const float4* p4 = reinterpret_cast<const float4*>(fp + (size_t)p * 16);
#pragma unroll
  for (int j = 0; j < 4; ++j) {
    float4 a = p4[j];
    r[4 * j] = a.x; r[4 * j + 1] = a.y; r[4 * j + 2] = a.z; r[4 * j + 3] = a.w;
  }
}
__device__ __forceinline__ void pack16(const float* r, uint32_t* u) {
#pragma unroll
  for (int j = 0; j < 8; ++j)
    u[j] = (uint32_t)f2bf(r[2 * j]) | ((uint32_t)f2bf(r[2 * j + 1]) << 16);
}
__device__ __forceinline__ void unpack16(const uint32_t* u, float* r) {
#pragma unroll
  for (int j = 0; j < 8; ++j) {
    r[2 * j]     = bf2f((unsigned short)(u[j] & 0xFFFFu));
    r[2 * j + 1] = bf2f((unsigned short)(u[j] >> 16));
  }
}

// sums over the 8 lanes sharing (lane&7); every lane gets its group's sum
__device__ __forceinline__ float hred(float v) {
  v += __shfl_xor(v, 8, 64);
  v += __shfl_xor(v, 16, 64);
  v += __shfl_xor(v, 32, 64);
  return v;
}

// block-reduce two 16-value stats into a 256-float per-block partial (no atomics)
__device__ __forceinline__ void stat_partial2(float* a, float* b, float* w4 /*[4*256]*/,
                                              float* dst, int tid) {
  const int wave = tid >> 6, lane = tid & 63;
#pragma unroll
  for (int d = 0; d < 16; ++d) { a[d] = hred(a[d]); b[d] = hred(b[d]); }
  if (lane < 8) {
#pragma unroll
    for (int d = 0; d < 16; ++d) {
      w4[wave * 256 + lane * 16 + d] = a[d];
      w4[wave * 256 + 128 + lane * 16 + d] = b[d];
    }
  }
  __syncthreads();
  dst[tid] = w4[tid] + w4[256 + tid] + w4[512 + tid] + w4[768 + tid];
}

// ================= fused cooperative kernel =================
__global__ __launch_bounds__(256, 4) void k_fused(
    const float* __restrict__ Q, const float* __restrict__ K, const float* __restrict__ V,
    const float* __restrict__ gamma, const float* __restrict__ beta,
    float* __restrict__ ws, float* __restrict__ out) {
  cg::grid_group grid = cg::this_grid();
  const int tid = threadIdx.x;
  const int blk = blockIdx.x;
  const int n = blk >> 8;          // 256 blocks per n
  const int h = tid & 7;
  const int p0 = blk * 512 + tid;  // block owns 512 pairs; 2 per thread
  const int p1 = p0 + 256;         // same head (256 % 8 == 0)

  __shared__ __align__(16) float smem[8608];  // 34432 B; carved per phase

  // persistent packed-bf16 sigmoid(Q), sigmoid(K) for both pairs (32 VGPRs)
  uint32_t uq[2][8], uk[2][8];

  // ---- Phase 1: load+sigmoid, pack, qsum/ksum partials
  {
    float sq[16], sk[16];
    {
      float q[16], k[16];
      load_sig_f32(Q, p0, q); load_sig_f32(K, p0, k);
      pack16(q, uq[0]); pack16(k, uk[0]);
#pragma unroll
      for (int d = 0; d < 16; ++d) { sq[d] = q[d]; sk[d] = k[d]; }
      load_sig_f32(Q, p1, q); load_sig_f32(K, p1, k);
      pack16(q, uq[1]); pack16(k, uk[1]);
#pragma unroll
      for (int d = 0; d < 16; ++d) { sq[d] += q[d]; sk[d] += k[d]; }
    }
    stat_partial2(sq, sk, smem, ws + P_A1 + blk * 256, tid);
  }
  grid.sync();

  // ---- R1: blocks 0..3 reduce qsum/ksum partials for n=blk
  if (blk < 4) {
    float acc = 0.f;
    const float* src = ws + P_A1 + (size_t)blk * 256 * 256;
#pragma unroll 8
    for (int c = 0; c < 256; ++c) acc += src[(size_t)c * 256 + tid];
    if (tid < 128) ws[F_QSUM + blk * 128 + tid] = acc;
    else ws[F_KSUM + blk * 128 + (tid - 128)] = acc;
  }
  grid.sync();

  // ---- Phase 2: qn = sum q*nr, kn = sum k*nc partials
  {
    float* ksE = smem;         // 128
    float* qsE = smem + 128;   // 128
    float* w4  = smem + 256;   // 1024
    if (tid < 128) {
      ksE[tid] = ws[F_KSUM + n * 128 + tid] + EPS;
      qsE[tid] = ws[F_QSUM + n * 128 + tid] + EPS;
    }
    __syncthreads();
    float qn[16], kn[16];
#pragma unroll
    for (int d = 0; d < 16; ++d) { qn[d] = 0.f; kn[d] = 0.f; }
#pragma unroll
    for (int j = 0; j < 2; ++j) {
      float q[16], k[16];
      unpack16(uq[j], q); unpack16(uk[j], k);
      float dr = 0.f, dc = 0.f;
#pragma unroll
      for (int d = 0; d < 16; ++d) {
        dr += (q[d] + EPS) * ksE[h * 16 + d];
        dc += (k[d] + EPS) * qsE[h * 16 + d];
      }
      const float nr = __fdividef(1.f, dr), nc = __fdividef(1.f, dc);
#pragma unroll
      for (int d = 0; d < 16; ++d) { qn[d] += q[d] * nr; kn[d] += k[d] * nc; }
    }
    stat_partial2(qn, kn, w4, ws + P_A2 + blk * 256, tid);
  }
  grid.sync();

  // ---- R2: blocks 0..3 reduce qn/kn partials
  if (blk < 4) {
    float acc = 0.f;
    const float* src = ws + P_A2 + (size_t)blk * 256 * 256;
#pragma unroll 8
    for (int c = 0; c < 256; ++c) acc += src[(size_t)c * 256 + tid];
    if (tid < 128) ws[F_QN + blk * 128 + tid] = acc;
    else ws[F_KN + blk * 128 + (tid - 128)] = acc;
  }
  grid.sync();

  // ---- Phase 3: w = exp(k.qnE), ssum, KV tile partials
  {
    constexpr int RS = 132;
    float* qnE = smem;           // 128
    float* ssb = smem + 128;     // 8 (+8 pad)
    float* kwL = smem + 144;     // 32*132 ; byte offset 576 (16-aligned)
    float* vL  = kwL + 32 * RS;  // 32*132
    if (tid < 128) qnE[tid] = ws[F_QN + n * 128 + tid] + EPS;
    if (tid < 8) ssb[tid] = 0.f;
    __syncthreads();
    const int ri = tid >> 3, lane = tid & 63, h2 = tid >> 5;
    const int d0 = ((tid >> 2) & 7) * 2;
    const int e0 = (tid & 3) * 4;
    float acc[2][4] = {{0.f, 0.f, 0.f, 0.f}, {0.f, 0.f, 0.f, 0.f}};
#pragma unroll
    for (int j = 0; j < 2; ++j) {
      float k[16], v[16];
      unpack16(uk[j], k);
      load_raw16(V, (j == 0) ? p0 : p1, v);
      float ncr = 0.f;
#pragma unroll
      for (int d = 0; d < 16; ++d) ncr += (k[d] + EPS) * qnE[h * 16 + d];
      const float w = __expf(ncr);   // ncr is O(1): no max-subtraction needed
      float sw = hred(w);
      if (lane < 8) atomicAdd(&ssb[lane], sw);
      const int wb = ri * RS + h * 16;
#pragma unroll
      for (int d = 0; d < 16; ++d) { kwL[wb + d] = k[d] * w; vL[wb + d] = v[d]; }
      __syncthreads();
      const int rb0 = h2 * 16;
#pragma unroll 4
      for (int r = 0; r < 32; ++r) {
        const int rb = r * RS + rb0;
        const float2 kk = *reinterpret_cast<const float2*>(&kwL[rb + d0]);
        const float4 vv = *reinterpret_cast<const float4*>(&vL[rb + e0]);
        acc[0][0] += kk.x * vv.x; acc[0][1] += kk.x * vv.y;
        acc[0][2] += kk.x * vv.z; acc[0][3] += kk.x * vv.w;
        acc[1][0] += kk.y * vv.x; acc[1][1] += kk.y * vv.y;
        acc[1][2] += kk.y * vv.z; acc[1][3] += kk.y * vv.w;
      }
      __syncthreads();
    }
    float* pk = ws + P_KV + (size_t)blk * 2048;
    *reinterpret_cast<float4*>(pk + h2 * 256 + d0 * 16 + e0) =
        make_float4(acc[0][0], acc[0][1], acc[0][2], acc[0][3]);
    *reinterpret_cast<float4*>(pk + h2 * 256 + (d0 + 1) * 16 + e0) =
        make_float4(acc[1][0], acc[1][1], acc[1][2], acc[1][3]);
    if (tid < 8) ws[P_SS + blk * 8 + tid] = ssb[tid];
  }
  grid.sync();

  // ---- R3: blocks 0..31 reduce KV partials; seg-0 blocks also reduce ssum
  if (blk < 32) {
    const int rn = blk >> 3, seg = blk & 7;
    const int i = seg * 256 + tid;
    float a = 0.f;
    const float* src = ws + P_KV + (size_t)rn * 256 * 2048;
#pragma unroll 8
    for (int c = 0; c < 256; ++c) a += src[(size_t)c * 2048 + i];
    ws[F_KV + rn * 2048 + i] = a;
    if (seg == 0 && tid < 8) {
      float s = 0.f;
      const float* ss = ws + P_SS + (size_t)rn * 256 * 8;
#pragma unroll 8
      for (int c = 0; c < 256; ++c) s += ss[c * 8 + tid];
      ws[F_SS + rn * 8 + tid] = s;
    }
  }
  grid.sync();

  // ---- Phase 4: x = q@kv * nr*nrr + v, LayerNorm, write out
  {
    float* kvs = smem;          // 8*260 = 2080 (pad 260: conflict-free by h)
    float* ksE = smem + 2080;   // 128
    float* knE = smem + 2208;   // 128
    float* gm  = smem + 2336;   // 16
    float* bt  = smem + 2352;   // 16
    float* ssE = smem + 2368;   // 8
    if (tid < 8) ssE[tid] = __fdividef((float)LL, ws[F_SS + n * 8 + tid]);
    if (tid >= 8 && tid < 136) {
      const int i = tid - 8;
      ksE[i] = ws[F_KSUM + n * 128 + i] + EPS;
      knE[i] = ws[F_KN + n * 128 + i] + EPS;
    }
    if (tid >= 136 && tid < 152) gm[tid - 136] = gamma[tid - 136];
    else if (tid >= 152 && tid < 168) bt[tid - 152] = beta[tid - 152];
    __syncthreads();
    for (int i = tid; i < 2048; i += 256) {
      const int hh = i >> 8, de = i & 255;
      kvs[hh * 260 + de] = ws[F_KV + n * 2048 + i] * ssE[hh];
    }
    __syncthreads();
#pragma unroll
    for (int j = 0; j < 2; ++j) {
      const int p = (j == 0) ? p0 : p1;
      float q[16], v[16];
      unpack16(uq[j], q);
      load_raw16(V, p, v);
      float dr = 0.f, drr = 0.f;
#pragma unroll
      for (int d = 0; d < 16; ++d) {
        const float qe = q[d] + EPS;
        dr += qe * ksE[h * 16 + d];
        drr += qe * knE[h * 16 + d];
      }
      const float sc = __fdividef(1.f, dr) * sigm(drr);
      float x[16];
#pragma unroll
      for (int e = 0; e < 16; ++e) x[e] = 0.f;
#pragma unroll
      for (int d = 0; d < 16; ++d) {
        const float qd = q[d];
        const float4* kr = reinterpret_cast<const float4*>(&kvs[h * 260 + d * 16]);
#pragma unroll
        for (int jj = 0; jj < 4; ++jj) {
          float4 a = kr[jj];
          x[4 * jj] += qd * a.x; x[4 * jj + 1] += qd * a.y;
          x[4 * jj + 2] += qd * a.z; x[4 * jj + 3] += qd * a.w;
        }
      }
#pragma unroll
      for (int e = 0; e < 16; ++e) x[e] = x[e] * sc + v[e];
      float mean = 0.f;
#pragma unroll
      for (int e = 0; e < 16; ++e) mean += x[e];
      mean *= (1.f / 16.f);
      float var = 0.f;
#pragma unroll
      for (int e = 0; e < 16; ++e) { const float t = x[e] - mean; var += t * t; }
      var *= (1.f / 16.f);
      const float inv = rsqrtf(var + LN_EPS);
#pragma unroll
      for (int e = 0; e < 16; ++e) x[e] = (x[e] - mean) * inv * gm[e] + bt[e];
      float4* op = reinterpret_cast<float4*>(out + (size_t)p * 16);
      op[0] = make_float4(x[0], x[1], x[2], x[3]);
      op[1] = make_float4(x[4], x[5], x[6], x[7]);
      op[2] = make_float4(x[8], x[9], x[10], x[11]);
      op[3] = make_float4(x[12], x[13], x[14], x[15]);
    }
  }
}

// ================= fallback: round-3 proven multi-kernel path =================
template <bool MIR>
__device__ __forceinline__ void fb_load_sig(const unsigned short* mir, const float* fp, int p, float* r) {
  if (MIR) {
    const uint4* p4 = reinterpret_cast<const uint4*>(mir + (size_t)p * 16);
    uint4 a = p4[0], b = p4[1];
    uint32_t w[8] = {a.x, a.y, a.z, a.w, b.x, b.y, b.z, b.w};
#pragma unroll
    for (int j = 0; j < 8; ++j) {
      r[2 * j]     = bf2f((unsigned short)(w[j] & 0xFFFFu));
      r[2 * j + 1] = bf2f((unsigned short)(w[j] >> 16));
    }
  } else {
    load_sig_f32(fp, p, r);
  }
}

__device__ __forceinline__ void fb_stat_atomic2(float* q, float* k, float* dQ, float* dK, int tid) {
  __shared__ float w4[4][256];
  const int wave = tid >> 6, lane = tid & 63;
#pragma unroll
  for (int d = 0; d < 16; ++d) { q[d] = hred(q[d]); k[d] = hred(k[d]); }
  if (lane < 8) {
#pragma unroll
    for (int d = 0; d < 16; ++d) {
      w4[wave][lane * 16 + d] = q[d];
      w4[wave][128 + lane * 16 + d] = k[d];
    }
  }
  __syncthreads();
  const float v = w4[0][tid] + w4[1][tid] + w4[2][tid] + w4[3][tid];
  if (tid < 128) atomicAdd(dQ + tid, v);
  else atomicAdd(dK + (tid - 128), v);
}

__device__ __forceinline__ void fb_stat_atomic1(float* q, float* dQ, int tid) {
  __shared__ float w1[4][128];
  const int wave = tid >> 6, lane = tid & 63;
#pragma unroll
  for (int d = 0; d < 16; ++d) q[d] = hred(q[d]);
  if (lane < 8) {
#pragma unroll
    for (int d = 0; d < 16; ++d) w1[wave][lane * 16 + d] = q[d];
  }
  __syncthreads();
  if (tid < 128) atomicAdd(dQ + tid, w1[0][tid] + w1[1][tid] + w1[2][tid] + w1[3][tid]);
}

__global__ __launch_bounds__(256) void fb_zero(float4* ws4) {
  const int i = blockIdx.x * 256 + threadIdx.x;
  if (i < FB_STATS_FLOATS / 4) ws4[i] = make_float4(0.f, 0.f, 0.f, 0.f);
}

template <bool MIR>
__global__ __launch_bounds__(256) void fb_prep(const float* __restrict__ Q, const float* __restrict__ K,
                                               float* __restrict__ ws,
                                               unsigned short* __restrict__ sQ, unsigned short* __restrict__ sK) {
  const int tid = threadIdx.x;
  const int n = blockIdx.x >> 7;
  const int b = blockIdx.x & 127;
  float sq[16], sk[16];
#pragma unroll
  for (int d = 0; d < 16; ++d) { sq[d] = 0.f; sk[d] = 0.f; }
#pragma unroll
  for (int c = 0; c < 4; ++c) {
    const int p = n * PAIRS_PER_N + (b * 4 + c) * 256 + tid;
    float q[16], k[16];
    load_sig_f32(Q, p, q);
    load_sig_f32(K, p, k);
    if (MIR) {
      uint32_t u[8];
      pack16(q, u);
      reinterpret_cast<uint4*>(sQ + (size_t)p * 16)[0] = make_uint4(u[0], u[1], u[2], u[3]);
      reinterpret_cast<uint4*>(sQ + (size_t)p * 16)[1] = make_uint4(u[4], u[5], u[6], u[7]);
      pack16(k, u);
      reinterpret_cast<uint4*>(sK + (size_t)p * 16)[0] = make_uint4(u[0], u[1], u[2], u[3]);
      reinterpret_cast<uint4*>(sK + (size_t)p * 16)[1] = make_uint4(u[4], u[5], u[6], u[7]);
    }
#pragma unroll
    for (int d = 0; d < 16; ++d) { sq[d] += q[d]; sk[d] += k[d]; }
  }
  fb_stat_atomic2(sq, sk, ws + FB_QSUM + n * 128, ws + FB_KSUM + n * 128, tid);
}

template <bool MIR>
__global__ __launch_bounds__(256) void fb_refq(const float* __restrict__ Q,
                                               const unsigned short* __restrict__ sQ,
                                               float* __restrict__ ws) {
  const int tid = threadIdx.x;
  const int n = blockIdx.x >> 7;
  const int b = blockIdx.x & 127;
  __shared__ float ksE[128];
  if (tid < 128) ksE[tid] = ws[FB_KSUM + n * 128 + tid] + EPS;
  __syncthreads();
  const int h = tid & 7;
  float qn[16];
#pragma unroll
  for (int d = 0; d < 16; ++d) qn[d] = 0.f;
#pragma unroll
  for (int c = 0; c < 4; ++c) {
    const int p = n * PAIRS_PER_N + (b * 4 + c) * 256 + tid;
    float q[16];
    fb_load_sig<MIR>(sQ, Q, p, q);
    float dr = 0.f;
#pragma unroll
    for (int d = 0; d < 16; ++d) dr += (q[d] + EPS) * ksE[h * 16 + d];
    const float nr = __fdividef(1.f, dr);
#pragma unroll
    for (int d = 0; d < 16; ++d) qn[d] += q[d] * nr;
  }
  fb_stat_atomic1(qn, ws + FB_QN + n * 128, tid);
}

template <bool MIR>
__global__ __launch_bounds__(256) void fb_kv(const float* __restrict__ K, const float* __restrict__ V,
                                             const unsigned short* __restrict__ sK,
                                             float* __restrict__ ws) {
  const int tid = threadIdx.x;
  const int n = blockIdx.x >> 6;
  const int b = blockIdx.x & 63;
  constexpr int RS = 132;
  __shared__ float qnE[128], qsE[128];
  __shared__ float ssb[8];
  __shared__ __align__(16) float kwL[32 * RS];
  __shared__ __align__(16) float vL[32 * RS];
  if (tid < 128) {
    qnE[tid] = ws[FB_QN + n * 128 + tid] + EPS;
    qsE[tid] = ws[FB_QSUM + n * 128 + tid] + EPS;
  }
  if (tid < 8) ssb[tid] = 0.f;
  __syncthreads();
  const int h = tid & 7, ri = tid >> 3, lane = tid & 63;
  const int h2 = tid >> 5;
  const int d0 = ((tid >> 2) & 7) * 2;
  const int e0 = (tid & 3) * 4;
  const int base = n * PAIRS_PER_N + b * 2048;
  float acc[2][4] = {{0.f, 0.f, 0.f, 0.f}, {0.f, 0.f, 0.f, 0.f}};
  float kn[16];
#pragma unroll
  for (int d = 0; d < 16; ++d) kn[d] = 0.f;
  float kb[2][16], vb[2][16];
  fb_load_sig<MIR>(sK, K, base + tid, kb[0]);
  load_raw16(V, base + tid, vb[0]);
#pragma unroll 2
  for (int t = 0; t < 8; ++t) {
    const int cur = t & 1, nxt = cur ^ 1;
    float* k = kb[cur];
    float* v = vb[cur];
    float dc = 0.f, ncr = 0.f;
#pragma unroll
    for (int d = 0; d < 16; ++d) {
      const float ke = k[d] + EPS;
      dc += ke * qsE[h * 16 + d];
      ncr += ke * qnE[h * 16 + d];
    }
    const float nc = __fdividef(1.f, dc);
#pragma unroll
    for (int d = 0; d < 16; ++d) kn[d] += k[d] * nc;
    const float w = __expf(ncr);
    float sw = hred(w);
    if (lane < 8) atomicAdd(&ssb[lane], sw);
    const int wb = ri * RS + h * 16;
#pragma unroll
    for (int d = 0; d < 16; ++d) { kwL[wb + d] = k[d] * w; vL[wb + d] = v[d]; }
    if (t < 7) {
      fb_load_sig<MIR>(sK, K, base + (t + 1) * 256 + tid, kb[nxt]);
      load_raw16(V, base + (t + 1) * 256 + tid, vb[nxt]);
    }
    __syncthreads();
    const int rb0 = h2 * 16;
#pragma unroll 4
    for (int r = 0; r < 32; ++r) {
      const int rb = r * RS + rb0;
      const float2 kk = *reinterpret_cast<const float2*>(&kwL[rb + d0]);
      const float4 vv = *reinterpret_cast<const float4*>(&vL[rb + e0]);
      acc[0][0] += kk.x * vv.x; acc[0][1] += kk.x * vv.y;
      acc[0][2] += kk.x * vv.z; acc[0][3] += kk.x * vv.w;
      acc[1][0] += kk.y * vv.x; acc[1][1] += kk.y * vv.y;
      acc[1][2] += kk.y * vv.z; acc[1][3] += kk.y * vv.w;
    }
    __syncthreads();
  }
  fb_stat_atomic1(kn, ws + FB_KN + n * 128, tid);
  if (tid < 8) atomicAdd(&ws[FB_SSUM + n * 8 + tid], ssb[tid]);
  float* kv = ws + FB_KVU + n * 2048 + h2 * 256;
#pragma unroll
  for (int j = 0; j < 4; ++j) atomicAdd(&kv[d0 * 16 + e0 + j], acc[0][j]);
#pragma unroll
  for (int j = 0; j < 4; ++j) atomicAdd(&kv[(d0 + 1) * 16 + e0 + j], acc[1][j]);
}

template <bool MIR>
__global__ __launch_bounds__(256) void fb_out(const float* __restrict__ Q, const float* __restrict__ V,
                                              const unsigned short* __restrict__ sQ,
                                              const float* __restrict__ gamma, const float* __restrict__ beta,
                                              const float* __restrict__ ws, float* __restrict__ out) {
  const int tid = threadIdx.x;
  const int p = blockIdx.x * 256 + tid;
  const int n = blockIdx.x >> 9;
  __shared__ __align__(16) float kvs[8 * 260];
  __shared__ float ksE[128], knE[128], gm[16], bt[16], ssE[8];
  if (tid < 8) ssE[tid] = __fdividef((float)LL, ws[FB_SSUM + n * 8 + tid]);
  if (tid >= 8 && tid < 136) {
    const int i = tid - 8;
    ksE[i] = ws[FB_KSUM + n * 128 + i] + EPS;
    knE[i] = ws[FB_KN + n * 128 + i] + EPS;
  }
  if (tid >= 136 && tid < 152) gm[tid - 136] = gamma[tid - 136];
  else if (tid >= 152 && tid < 168) bt[tid - 152] = beta[tid - 152];
  __syncthreads();
  for (int i = tid; i < 2048; i += 256) {
    const int hh = i >> 8, de = i & 255;
    kvs[hh * 260 + de] = ws[FB_KVU + n * 2048 + i] * ssE[hh];
  }
  __syncthreads();
  const int h = tid & 7;
  float q[16], v[16];
  fb_load_sig<MIR>(sQ, Q, p, q);
  load_raw16(V, p, v);
  float dr = 0.f, drr = 0.f;
#pragma unroll
  for (int d = 0; d < 16; ++d) {
    const float qe = q[d] + EPS;
    dr += qe * ksE[h * 16 + d];
    drr += qe * knE[h * 16 + d];
  }
  const float sc = __fdividef(1.f, dr) * sigm(drr);
  float x[16];
#pragma unroll
  for (int e = 0; e < 16; ++e) x[e] = 0.f;
#pragma unroll
  for (int d = 0; d < 16; ++d) {
    const float qd = q[d];
    const float4* kr = reinterpret_cast<const float4*>(&kvs[h * 260 + d * 16]);
#pragma unroll
    for (int j = 0; j < 4; ++j) {
      float4 a = kr[j];
      x[4 * j] += qd * a.x; x[4 * j + 1] += qd * a.y;
      x[4 * j + 2] += qd * a.z; x[4 * j + 3] += qd * a.w;
    }
  }
#pragma unroll
  for (int e = 0; e < 16; ++e) x[e] = x[e] * sc + v[e];
  float mean = 0.f;
#pragma unroll
  for (int e = 0; e < 16; ++e) mean += x[e];
  mean *= (1.f / 16.f);
  float var = 0.f;
#pragma unroll
  for (int e = 0; e < 16; ++e) { const float t = x[e] - mean; var += t * t; }
  var *= (1.f / 16.f);
  const float inv = rsqrtf(var + LN_EPS);
#pragma unroll
  for (int e = 0; e < 16; ++e) x[e] = (x[e] - mean) * inv * gm[e] + bt[e];
  float4* op = reinterpret_cast<float4*>(out + (size_t)p * 16);
  op[0] = make_float4(x[0], x[1], x[2], x[3]);
  op[1] = make_float4(x[4], x[5], x[6], x[7]);
  op[2] = make_float4(x[8], x[9], x[10], x[11]);
  op[3] = make_float4(x[12], x[13], x[14], x[15]);
}

extern "C" void kernel_launch(void* const* d_in, const int* in_sizes, int n_in,
                              void* d_out, int out_size, void* d_ws, size_t ws_size,
                              hipStream_t stream) {
  const float* Q = (const float*)d_in[0];
  const float* K = (const float*)d_in[1];
  const float* V = (const float*)d_in[2];
  const float* gamma = (const float*)d_in[3];
  const float* beta = (const float*)d_in[4];
  float* ws = (float*)d_ws;
  float* out = (float*)d_out;

  // primary: single fused cooperative kernel (no atomics, no mirrors)
  bool ok = false;
  if (ws_size >= WS_FUSED) {
    void* args[] = {(void*)&Q, (void*)&K, (void*)&V, (void*)&gamma, (void*)&beta,
                    (void*)&ws, (void*)&out};
    hipError_t err = hipLaunchCooperativeKernel(reinterpret_cast<void*>(&k_fused),
                                                dim3(GRID), dim3(256), args, 0, stream);
    ok = (err == hipSuccess);
    if (!ok) (void)hipGetLastError();  // clear sticky error before fallback
  }
  if (ok) return;

  // fallback: proven round-3 multi-kernel path
  unsigned short* sQ = (unsigned short*)((char*)d_ws + FB_MIR_Q_BYTE);
  unsigned short* sK = (unsigned short*)((char*)d_ws + FB_MIR_K_BYTE);
  const dim3 blk(256);
  const int gPrep = 512;
  const int gKv = 256;
  const int gOut = NPAIR / 256;
  const int gZero = (FB_STATS_FLOATS / 4 + 255) / 256;

  fb_zero<<<gZero, blk, 0, stream>>>(reinterpret_cast<float4*>(ws));
  if (ws_size >= FB_WS_FULL) {
    fb_prep<true><<<gPrep, blk, 0, stream>>>(Q, K, ws, sQ, sK);
    fb_refq<true><<<gPrep, blk, 0, stream>>>(Q, sQ, ws);
    fb_kv<true><<<gKv, blk, 0, stream>>>(K, V, sK, ws);
    fb_out<true><<<gOut, blk, 0, stream>>>(Q, V, sQ, gamma, beta, ws, out);
  } else {
    fb_prep<false><<<gPrep, blk, 0, stream>>>(Q, K, ws, nullptr, nullptr);
    fb_refq<false><<<gPrep, blk, 0, stream>>>(Q, nullptr, ws);
    fb_kv<false><<<gKv, blk, 0, stream>>>(K, V, nullptr, ws);
    fb_out<false><<<gOut, blk, 0, stream>>>(Q, V, nullptr, gamma, beta, ws, out);
  }
}

// Round 6
// 234.831 us; speedup vs baseline: 4.8710x; 4.8710x over previous
//
#include <hip/hip_runtime.h>
#include <math.h>
#include <stdint.h>

constexpr int LL = 16384;
constexpr int NROW = 65536;             // N*L
constexpr int NPAIR = NROW * 8;         // 524288 (row,head) pairs
constexpr int PAIRS_PER_N = NPAIR / 4;  // 131072
constexpr float EPS = 1e-6f;
constexpr float LN_EPS = 1e-5f;

// ---------------- workspace layout (all deterministic, no atomics) ----------------
// finals
constexpr int F_KSUM = 0;               // [4][128]
constexpr int F_KN   = 512;             // [4][128]
constexpr int F_SS   = 1024;            // [4][8]
constexpr int F_KV   = 1056;            // [4][2048]   (ends 9248)
// per-block partials (fully overwritten each run; no zeroing needed)
constexpr int P_A1 = 9472;                    // [4][128][256] qsum|ksum per prep block
constexpr int P_A2 = P_A1 + 4 * 128 * 256;    // [4][128][128] qn per refq block
constexpr int P_KN = P_A2 + 4 * 128 * 128;    // [4][256][128] kn per kv block
constexpr int P_SS = P_KN + 4 * 256 * 128;    // [4][256][8]   ssum per kv block
constexpr int P_KV = P_SS + 4 * 256 * 8;      // [4][256][2048] KV per kv block
constexpr int FLOAT_END = P_KV + 4 * 256 * 2048;  // 2442496 floats ≈ 9.77 MB
constexpr size_t MIR_Q_BYTE = (size_t)FLOAT_END * 4;
constexpr size_t MIR_ELEMS  = (size_t)NPAIR * 16;
constexpr size_t MIR_K_BYTE = MIR_Q_BYTE + MIR_ELEMS * 2;
constexpr size_t WS_FULL    = MIR_K_BYTE + MIR_ELEMS * 2;   // ~43.3 MB

__device__ __forceinline__ float sigm(float x) { return __fdividef(1.f, 1.f + __expf(-x)); }
__device__ __forceinline__ unsigned short f2bf(float f) {
  uint32_t x = __float_as_uint(f);
  return (unsigned short)((x + 0x7FFFu + ((x >> 16) & 1u)) >> 16);
}
__device__ __forceinline__ float bf2f(unsigned short u) {
  return __uint_as_float(((uint32_t)u) << 16);
}

template <bool MIR>
__device__ __forceinline__ void load_sig(const unsigned short* mir, const float* fp, int p, float* r) {
  if (MIR) {
    const uint4* p4 = reinterpret_cast<const uint4*>(mir + (size_t)p * 16);
    uint4 a = p4[0], b = p4[1];
    uint32_t w[8] = {a.x, a.y, a.z, a.w, b.x, b.y, b.z, b.w};
#pragma unroll
    for (int j = 0; j < 8; ++j) {
      r[2 * j]     = bf2f((unsigned short)(w[j] & 0xFFFFu));
      r[2 * j + 1] = bf2f((unsigned short)(w[j] >> 16));
    }
  } else {
    const float4* p4 = reinterpret_cast<const float4*>(fp + (size_t)p * 16);
#pragma unroll
    for (int j = 0; j < 4; ++j) {
      float4 a = p4[j];
      r[4 * j] = sigm(a.x); r[4 * j + 1] = sigm(a.y);
      r[4 * j + 2] = sigm(a.z); r[4 * j + 3] = sigm(a.w);
    }
  }
}
__device__ __forceinline__ void load_raw16(const float* fp, int p, float* r) {
  const float4* p4 = reinterpret_cast<const float4*>(fp + (size_t)p * 16);
#pragma unroll
  for (int j = 0; j < 4; ++j) {
    float4 a = p4[j];
    r[4 * j] = a.x; r[4 * j + 1] = a.y; r[4 * j + 2] = a.z; r[4 * j + 3] = a.w;
  }
}

// sums over the 8 lanes sharing (lane&7); every lane gets its group's sum
__device__ __forceinline__ float hred(float v) {
  v += __shfl_xor(v, 8, 64);
  v += __shfl_xor(v, 16, 64);
  v += __shfl_xor(v, 32, 64);
  return v;
}

// block-reduce two 16-value stats into a 256-float per-block partial (no atomics)
__device__ __forceinline__ void stat_partial2(float* a, float* b, float* w4 /*[1024]*/,
                                              float* dst, int tid) {
  const int wave = tid >> 6, lane = tid & 63;
#pragma unroll
  for (int d = 0; d < 16; ++d) { a[d] = hred(a[d]); b[d] = hred(b[d]); }
  if (lane < 8) {
#pragma unroll
    for (int d = 0; d < 16; ++d) {
      w4[wave * 256 + lane * 16 + d] = a[d];
      w4[wave * 256 + 128 + lane * 16 + d] = b[d];
    }
  }
  __syncthreads();
  dst[tid] = w4[tid] + w4[256 + tid] + w4[512 + tid] + w4[768 + tid];
}

// block-reduce one 16-value stat into a 128-float per-block partial
__device__ __forceinline__ void stat_partial1(float* a, float* w1 /*[512]*/,
                                              float* dst, int tid) {
  const int wave = tid >> 6, lane = tid & 63;
#pragma unroll
  for (int d = 0; d < 16; ++d) a[d] = hred(a[d]);
  if (lane < 8) {
#pragma unroll
    for (int d = 0; d < 16; ++d) w1[wave * 128 + lane * 16 + d] = a[d];
  }
  __syncthreads();
  if (tid < 128) dst[tid] = w1[tid] + w1[128 + tid] + w1[256 + tid] + w1[384 + tid];
}

// Pass 1: sigmoid, bf16 mirrors, per-block qsum/ksum partials. 512 blocks x 4 chunks.
template <bool MIR>
__global__ __launch_bounds__(256) void k_prep(const float* __restrict__ Q, const float* __restrict__ K,
                                              float* __restrict__ ws,
                                              unsigned short* __restrict__ sQ, unsigned short* __restrict__ sK) {
  const int tid = threadIdx.x;
  const int n = blockIdx.x >> 7;       // 128 blocks per n
  const int b = blockIdx.x & 127;
  __shared__ float w4[1024];
  float sq[16], sk[16];
#pragma unroll
  for (int d = 0; d < 16; ++d) { sq[d] = 0.f; sk[d] = 0.f; }
#pragma unroll
  for (int c = 0; c < 4; ++c) {
    const int p = n * PAIRS_PER_N + (b * 4 + c) * 256 + tid;
    float q[16], k[16];
    load_sig<false>(nullptr, Q, p, q);
    load_sig<false>(nullptr, K, p, k);
    if (MIR) {
      union U { unsigned short u[8]; uint4 v; };
      U a, bb;
#pragma unroll
      for (int j = 0; j < 8; ++j) { a.u[j] = f2bf(q[j]); bb.u[j] = f2bf(q[8 + j]); }
      uint4* dq = reinterpret_cast<uint4*>(sQ + (size_t)p * 16);
      dq[0] = a.v; dq[1] = bb.v;
#pragma unroll
      for (int j = 0; j < 8; ++j) { a.u[j] = f2bf(k[j]); bb.u[j] = f2bf(k[8 + j]); }
      uint4* dk = reinterpret_cast<uint4*>(sK + (size_t)p * 16);
      dk[0] = a.v; dk[1] = bb.v;
    }
#pragma unroll
    for (int d = 0; d < 16; ++d) { sq[d] += q[d]; sk[d] += k[d]; }
  }
  stat_partial2(sq, sk, w4, ws + P_A1 + (size_t)blockIdx.x * 256, tid);
}

// Pass 2: qn = sum_l q*nr partials. Each block first sums ksum from prep partials
// (L2-hot, deterministic), then accumulates its 4 chunks. 512 blocks.
template <bool MIR>
__global__ __launch_bounds__(256) void k_refq(const float* __restrict__ Q,
                                              const unsigned short* __restrict__ sQ,
                                              float* __restrict__ ws) {
  const int tid = threadIdx.x;
  const int n = blockIdx.x >> 7;
  const int b = blockIdx.x & 127;
  __shared__ float ksE[128];
  __shared__ float w1[512];
  // ksum = sum over 128 prep-partials (k-half), split across 256 threads
  {
    const int i = tid & 127, half = tid >> 7;
    float a = 0.f;
    const float* src = ws + P_A1 + ((size_t)(n * 128 + half * 64)) * 256 + 128 + i;
#pragma unroll 4
    for (int c = 0; c < 64; ++c) a += src[(size_t)c * 256];
    w1[tid] = a;
    __syncthreads();
    if (tid < 128) ksE[tid] = w1[tid] + w1[128 + tid] + EPS;
    __syncthreads();
  }
  const int h = tid & 7;
  float qn[16];
#pragma unroll
  for (int d = 0; d < 16; ++d) qn[d] = 0.f;
#pragma unroll
  for (int c = 0; c < 4; ++c) {
    const int p = n * PAIRS_PER_N + (b * 4 + c) * 256 + tid;
    float q[16];
    load_sig<MIR>(sQ, Q, p, q);
    float dr = 0.f;
#pragma unroll
    for (int d = 0; d < 16; ++d) dr += (q[d] + EPS) * ksE[h * 16 + d];
    const float nr = __fdividef(1.f, dr);
#pragma unroll
    for (int d = 0; d < 16; ++d) qn[d] += q[d] * nr;
  }
  stat_partial1(qn, w1, ws + P_A2 + (size_t)blockIdx.x * 128, tid);
}

// Pass 3: nc/kn, refine weight w = exp(k.qnE), ssum, weighted-KV tile partials.
// 1024 blocks (4/CU) x 2 tiles of 32 rows; qsum/qn summed from partials at entry;
// register double-buffer prefetch; per-block partial writes (no atomics).
template <bool MIR>
__global__ __launch_bounds__(256) void k_kv(const float* __restrict__ K, const float* __restrict__ V,
                                            const unsigned short* __restrict__ sK,
                                            float* __restrict__ ws) {
  const int tid = threadIdx.x;
  const int n = blockIdx.x >> 8;       // 256 blocks per n
  const int b = blockIdx.x & 255;
  constexpr int RS = 132;              // row stride: head-stride 16 (aligned wide reads), +4 pad
  __shared__ float qnE[128], qsE[128];
  __shared__ float ssb[8];
  __shared__ float w1[512];
  __shared__ __align__(16) float kwL[32 * RS];
  __shared__ __align__(16) float vL[32 * RS];
  // qsum (prep partials q-half) and qn (refq partials), 2-way split over 256 threads
  {
    const int i = tid & 127, half = tid >> 7;
    float a = 0.f;
    const float* src = ws + P_A1 + ((size_t)(n * 128 + half * 64)) * 256 + i;
#pragma unroll 4
    for (int c = 0; c < 64; ++c) a += src[(size_t)c * 256];
    w1[tid] = a;
    __syncthreads();
    if (tid < 128) qsE[tid] = w1[tid] + w1[128 + tid] + EPS;
    __syncthreads();
    float bb = 0.f;
    const float* src2 = ws + P_A2 + ((size_t)(n * 128 + half * 64)) * 128 + i;
#pragma unroll 4
    for (int c = 0; c < 64; ++c) bb += src2[(size_t)c * 128];
    w1[tid] = bb;
    __syncthreads();
    if (tid < 128) qnE[tid] = w1[tid] + w1[128 + tid] + EPS;
    if (tid < 8) ssb[tid] = 0.f;
    __syncthreads();
  }
  const int h = tid & 7, ri = tid >> 3, lane = tid & 63;
  const int h2 = tid >> 5;
  const int d0 = ((tid >> 2) & 7) * 2;
  const int e0 = (tid & 3) * 4;
  const int base = n * PAIRS_PER_N + b * 512;   // 2 tiles x 256 pairs
  float acc[2][4] = {{0.f, 0.f, 0.f, 0.f}, {0.f, 0.f, 0.f, 0.f}};
  float kn[16];
#pragma unroll
  for (int d = 0; d < 16; ++d) kn[d] = 0.f;
  float kb[2][16], vb[2][16];
  load_sig<MIR>(sK, K, base + tid, kb[0]);
  load_raw16(V, base + tid, vb[0]);
#pragma unroll
  for (int t = 0; t < 2; ++t) {      // fully unrolled: kb/vb indices static
    float* k = kb[t];
    float* v = vb[t];
    float dc = 0.f, ncr = 0.f;
#pragma unroll
    for (int d = 0; d < 16; ++d) {
      const float ke = k[d] + EPS;
      dc += ke * qsE[h * 16 + d];
      ncr += ke * qnE[h * 16 + d];
    }
    const float nc = __fdividef(1.f, dc);
#pragma unroll
    for (int d = 0; d < 16; ++d) kn[d] += k[d] * nc;
    const float w = __expf(ncr);   // ncr is O(1): no max-subtraction needed
    float sw = hred(w);
    if (lane < 8) atomicAdd(&ssb[lane], sw);   // LDS atomic, 8 addresses
    const int wb = ri * RS + h * 16;
#pragma unroll
    for (int d = 0; d < 16; ++d) { kwL[wb + d] = k[d] * w; vL[wb + d] = v[d]; }
    // prefetch next tile before the barrier; loads stay in flight across it
    if (t < 1) {
      load_sig<MIR>(sK, K, base + 256 + tid, kb[1]);
      load_raw16(V, base + 256 + tid, vb[1]);
    }
    __syncthreads();
    const int rb0 = h2 * 16;
#pragma unroll 4
    for (int r = 0; r < 32; ++r) {
      const int rb = r * RS + rb0;
      const float2 kk = *reinterpret_cast<const float2*>(&kwL[rb + d0]);
      const float4 vv = *reinterpret_cast<const float4*>(&vL[rb + e0]);
      acc[0][0] += kk.x * vv.x; acc[0][1] += kk.x * vv.y;
      acc[0][2] += kk.x * vv.z; acc[0][3] += kk.x * vv.w;
      acc[1][0] += kk.y * vv.x; acc[1][1] += kk.y * vv.y;
      acc[1][2] += kk.y * vv.z; acc[1][3] += kk.y * vv.w;
    }
    __syncthreads();
  }
  // per-block partial writes (deterministic)
  stat_partial1(kn, w1, ws + P_KN + (size_t)blockIdx.x * 128, tid);
  if (tid < 8) ws[P_SS + (size_t)blockIdx.x * 8 + tid] = ssb[tid];
  float* pk = ws + P_KV + (size_t)blockIdx.x * 2048;
  *reinterpret_cast<float4*>(pk + h2 * 256 + d0 * 16 + e0) =
      make_float4(acc[0][0], acc[0][1], acc[0][2], acc[0][3]);
  *reinterpret_cast<float4*>(pk + h2 * 256 + (d0 + 1) * 16 + e0) =
      make_float4(acc[1][0], acc[1][1], acc[1][2], acc[1][3]);
}

// Reduce KV/kn/ssum/ksum partials to finals. 32 blocks (4n x 8seg), deterministic.
__global__ __launch_bounds__(256) void k_kvred(float* __restrict__ ws) {
  const int tid = threadIdx.x;
  const int n = blockIdx.x >> 3, seg = blockIdx.x & 7;
  // KV: each block reduces one 256-float segment over 256 kv-partials
  {
    float a = 0.f;
    const float* src = ws + P_KV + (size_t)n * 256 * 2048 + seg * 256 + tid;
#pragma unroll 4
    for (int c = 0; c < 256; ++c) a += src[(size_t)c * 2048];
    ws[F_KV + n * 2048 + seg * 256 + tid] = a;
  }
  if (seg == 0 && tid < 128) {        // kn
    float s = 0.f;
    const float* src = ws + P_KN + (size_t)n * 256 * 128 + tid;
#pragma unroll 4
    for (int c = 0; c < 256; ++c) s += src[(size_t)c * 128];
    ws[F_KN + n * 128 + tid] = s;
  }
  if (seg == 1 && tid < 8) {          // ssum
    float s = 0.f;
    const float* src = ws + P_SS + (size_t)n * 256 * 8 + tid;
#pragma unroll 4
    for (int c = 0; c < 256; ++c) s += src[(size_t)c * 8];
    ws[F_SS + n * 8 + tid] = s;
  }
  if (seg == 2 && tid < 128) {        // ksum (k-half of prep partials)
    float s = 0.f;
    const float* src = ws + P_A1 + (size_t)n * 128 * 256 + 128 + tid;
#pragma unroll 4
    for (int c = 0; c < 128; ++c) s += src[(size_t)c * 256];
    ws[F_KSUM + n * 128 + tid] = s;
  }
}

// Pass 4: x = q@kv * nr * nrr + v, LayerNorm, write out. Reads finals only.
template <bool MIR>
__global__ __launch_bounds__(256) void k_out(const float* __restrict__ Q, const float* __restrict__ V,
                                             const unsigned short* __restrict__ sQ,
                                             const float* __restrict__ gamma, const float* __restrict__ beta,
                                             const float* __restrict__ ws, float* __restrict__ out) {
  const int tid = threadIdx.x;
  const int p = blockIdx.x * 256 + tid;
  const int n = blockIdx.x >> 9;
  __shared__ __align__(16) float kvs[8 * 260];  // pad 260 → conflict-free by h
  __shared__ float ksE[128], knE[128], gm[16], bt[16], ssE[8];
  if (tid < 8) ssE[tid] = __fdividef((float)LL, ws[F_SS + n * 8 + tid]);
  if (tid >= 8 && tid < 136) {
    const int i = tid - 8;
    ksE[i] = ws[F_KSUM + n * 128 + i] + EPS;
    knE[i] = ws[F_KN + n * 128 + i] + EPS;
  }
  if (tid >= 136 && tid < 152) gm[tid - 136] = gamma[tid - 136];
  else if (tid >= 152 && tid < 168) bt[tid - 152] = beta[tid - 152];
  __syncthreads();
  for (int i = tid; i < 2048; i += 256) {
    const int hh = i >> 8, de = i & 255;
    kvs[hh * 260 + de] = ws[F_KV + n * 2048 + i] * ssE[hh];
  }
  __syncthreads();
  const int h = tid & 7;
  float q[16], v[16];
  load_sig<MIR>(sQ, Q, p, q);
  load_raw16(V, p, v);
  float dr = 0.f, drr = 0.f;
#pragma unroll
  for (int d = 0; d < 16; ++d) {
    const float qe = q[d] + EPS;
    dr += qe * ksE[h * 16 + d];
    drr += qe * knE[h * 16 + d];
  }
  const float sc = __fdividef(1.f, dr) * sigm(drr);
  float x[16];
#pragma unroll
  for (int e = 0; e < 16; ++e) x[e] = 0.f;
#pragma unroll
  for (int d = 0; d < 16; ++d) {
    const float qd = q[d];
    const float4* kr = reinterpret_cast<const float4*>(&kvs[h * 260 + d * 16]);
#pragma unroll
    for (int j = 0; j < 4; ++j) {
      float4 a = kr[j];
      x[4 * j] += qd * a.x; x[4 * j + 1] += qd * a.y;
      x[4 * j + 2] += qd * a.z; x[4 * j + 3] += qd * a.w;
    }
  }
#pragma unroll
  for (int e = 0; e < 16; ++e) x[e] = x[e] * sc + v[e];
  float mean = 0.f;
#pragma unroll
  for (int e = 0; e < 16; ++e) mean += x[e];
  mean *= (1.f / 16.f);
  float var = 0.f;
#pragma unroll
  for (int e = 0; e < 16; ++e) { const float t = x[e] - mean; var += t * t; }
  var *= (1.f / 16.f);
  const float inv = rsqrtf(var + LN_EPS);
#pragma unroll
  for (int e = 0; e < 16; ++e) x[e] = (x[e] - mean) * inv * gm[e] + bt[e];
  float4* op = reinterpret_cast<float4*>(out + (size_t)p * 16);
  op[0] = make_float4(x[0], x[1], x[2], x[3]);
  op[1] = make_float4(x[4], x[5], x[6], x[7]);
  op[2] = make_float4(x[8], x[9], x[10], x[11]);
  op[3] = make_float4(x[12], x[13], x[14], x[15]);
}

extern "C" void kernel_launch(void* const* d_in, const int* in_sizes, int n_in,
                              void* d_out, int out_size, void* d_ws, size_t ws_size,
                              hipStream_t stream) {
  const float* Q = (const float*)d_in[0];
  const float* K = (const float*)d_in[1];
  const float* V = (const float*)d_in[2];
  const float* gamma = (const float*)d_in[3];
  const float* beta = (const float*)d_in[4];
  float* ws = (float*)d_ws;
  float* out = (float*)d_out;
  unsigned short* sQ = (unsigned short*)((char*)d_ws + MIR_Q_BYTE);
  unsigned short* sK = (unsigned short*)((char*)d_ws + MIR_K_BYTE);

  const dim3 blk(256);
  const int gPrep = 512;               // 128 blocks/n x 4 chunks
  const int gKv = 1024;                // 256 blocks/n x 2 tiles (4 blocks/CU)
  const int gOut = NPAIR / 256;        // 2048

  if (ws_size >= WS_FULL) {
    k_prep<true><<<gPrep, blk, 0, stream>>>(Q, K, ws, sQ, sK);
    k_refq<true><<<gPrep, blk, 0, stream>>>(Q, sQ, ws);
    k_kv<true><<<gKv, blk, 0, stream>>>(K, V, sK, ws);
    k_kvred<<<32, blk, 0, stream>>>(ws);
    k_out<true><<<gOut, blk, 0, stream>>>(Q, V, sQ, gamma, beta, ws, out);
  } else {
    k_prep<false><<<gPrep, blk, 0, stream>>>(Q, K, ws, nullptr, nullptr);
    k_refq<false><<<gPrep, blk, 0, stream>>>(Q, nullptr, ws);
    k_kv<false><<<gKv, blk, 0, stream>>>(K, V, nullptr, ws);
    k_kvred<<<32, blk, 0, stream>>>(ws);
    k_out<false><<<gOut, blk, 0, stream>>>(Q, V, nullptr, gamma, beta, ws, out);
  }
}

// Round 7
// 200.582 us; speedup vs baseline: 5.7027x; 1.1707x over previous
//
#include <hip/hip_runtime.h>
#include <math.h>
#include <stdint.h>

constexpr int LL = 16384;
constexpr int NROW = 65536;             // N*L
constexpr int NPAIR = NROW * 8;         // 524288 (row,head) pairs
constexpr int PAIRS_PER_N = NPAIR / 4;  // 131072
constexpr float EPS = 1e-6f;
constexpr float LN_EPS = 1e-5f;

// ---------------- workspace layout (deterministic, no atomics) ----------------
// finals
constexpr int F_KSUM = 0;               // [4][128]
constexpr int F_KN   = 512;             // [4][128]
constexpr int F_SS   = 1024;            // [4][8]
constexpr int F_QSUM = 1056;            // [4][128]
constexpr int F_QN   = 1568;            // [4][128]
constexpr int F_KV   = 2080;            // [4][2048]  (ends 10272)
// per-block partials (fully overwritten each run; no zeroing needed)
constexpr int P_A1 = 10272;                     // [2048][256] qsum|ksum per prep block
constexpr int P_A2 = P_A1 + 2048 * 256;         // [2048][128] qn per refq block
constexpr int P_KN = P_A2 + 2048 * 128;         // [2048][128] kn per kv block
constexpr int P_SS = P_KN + 2048 * 128;         // [2048][8]   ssum per kv block
constexpr int P_KV = P_SS + 2048 * 8;           // [2048][2048] KV per kv block
constexpr int FLOAT_END = P_KV + 2048 * 2048;   // ≈ 5.27M floats ≈ 21.1 MB
constexpr size_t MIR_Q_BYTE = (size_t)FLOAT_END * 4;
constexpr size_t MIR_ELEMS  = (size_t)NPAIR * 16;
constexpr size_t MIR_K_BYTE = MIR_Q_BYTE + MIR_ELEMS * 2;
constexpr size_t WS_FULL    = MIR_K_BYTE + MIR_ELEMS * 2;   // ~54.7 MB

__device__ __forceinline__ float sigm(float x) { return __fdividef(1.f, 1.f + __expf(-x)); }
__device__ __forceinline__ unsigned short f2bf(float f) {
  uint32_t x = __float_as_uint(f);
  return (unsigned short)((x + 0x7FFFu + ((x >> 16) & 1u)) >> 16);
}
__device__ __forceinline__ float bf2f(unsigned short u) {
  return __uint_as_float(((uint32_t)u) << 16);
}

template <bool MIR>
__device__ __forceinline__ void load_sig(const unsigned short* mir, const float* fp, int p, float* r) {
  if (MIR) {
    const uint4* p4 = reinterpret_cast<const uint4*>(mir + (size_t)p * 16);
    uint4 a = p4[0], b = p4[1];
    uint32_t w[8] = {a.x, a.y, a.z, a.w, b.x, b.y, b.z, b.w};
#pragma unroll
    for (int j = 0; j < 8; ++j) {
      r[2 * j]     = bf2f((unsigned short)(w[j] & 0xFFFFu));
      r[2 * j + 1] = bf2f((unsigned short)(w[j] >> 16));
    }
  } else {
    const float4* p4 = reinterpret_cast<const float4*>(fp + (size_t)p * 16);
#pragma unroll
    for (int j = 0; j < 4; ++j) {
      float4 a = p4[j];
      r[4 * j] = sigm(a.x); r[4 * j + 1] = sigm(a.y);
      r[4 * j + 2] = sigm(a.z); r[4 * j + 3] = sigm(a.w);
    }
  }
}
__device__ __forceinline__ void load_raw16(const float* fp, int p, float* r) {
  const float4* p4 = reinterpret_cast<const float4*>(fp + (size_t)p * 16);
#pragma unroll
  for (int j = 0; j < 4; ++j) {
    float4 a = p4[j];
    r[4 * j] = a.x; r[4 * j + 1] = a.y; r[4 * j + 2] = a.z; r[4 * j + 3] = a.w;
  }
}

// sums over the 8 lanes sharing (lane&7); every lane gets its group's sum
__device__ __forceinline__ float hred(float v) {
  v += __shfl_xor(v, 8, 64);
  v += __shfl_xor(v, 16, 64);
  v += __shfl_xor(v, 32, 64);
  return v;
}

// block-reduce two 16-value stats into a 256-float per-block partial
__device__ __forceinline__ void stat_partial2(float* a, float* b, float* w4 /*[1024]*/,
                                              float* dst, int tid) {
  const int wave = tid >> 6, lane = tid & 63;
#pragma unroll
  for (int d = 0; d < 16; ++d) { a[d] = hred(a[d]); b[d] = hred(b[d]); }
  if (lane < 8) {
#pragma unroll
    for (int d = 0; d < 16; ++d) {
      w4[wave * 256 + lane * 16 + d] = a[d];
      w4[wave * 256 + 128 + lane * 16 + d] = b[d];
    }
  }
  __syncthreads();
  dst[tid] = w4[tid] + w4[256 + tid] + w4[512 + tid] + w4[768 + tid];
}

// block-reduce one 16-value stat into a 128-float per-block partial
__device__ __forceinline__ void stat_partial1(float* a, float* w1 /*[512]*/,
                                              float* dst, int tid) {
  const int wave = tid >> 6, lane = tid & 63;
#pragma unroll
  for (int d = 0; d < 16; ++d) a[d] = hred(a[d]);
  if (lane < 8) {
#pragma unroll
    for (int d = 0; d < 16; ++d) w1[wave * 128 + lane * 16 + d] = a[d];
  }
  __syncthreads();
  if (tid < 128) dst[tid] = w1[tid] + w1[128 + tid] + w1[256 + tid] + w1[384 + tid];
}

// Pass 1: sigmoid, bf16 mirrors, per-block qsum/ksum partials. 2048 blocks (8/CU).
template <bool MIR>
__global__ __launch_bounds__(256) void k_prep(const float* __restrict__ Q, const float* __restrict__ K,
                                              float* __restrict__ ws,
                                              unsigned short* __restrict__ sQ, unsigned short* __restrict__ sK) {
  const int tid = threadIdx.x;
  const int p = blockIdx.x * 256 + tid;
  __shared__ float w4[1024];
  float q[16], k[16];
  load_sig<false>(nullptr, Q, p, q);
  load_sig<false>(nullptr, K, p, k);
  if (MIR) {
    union U { unsigned short u[8]; uint4 v; };
    U a, bb;
#pragma unroll
    for (int j = 0; j < 8; ++j) { a.u[j] = f2bf(q[j]); bb.u[j] = f2bf(q[8 + j]); }
    uint4* dq = reinterpret_cast<uint4*>(sQ + (size_t)p * 16);
    dq[0] = a.v; dq[1] = bb.v;
#pragma unroll
    for (int j = 0; j < 8; ++j) { a.u[j] = f2bf(k[j]); bb.u[j] = f2bf(k[8 + j]); }
    uint4* dk = reinterpret_cast<uint4*>(sK + (size_t)p * 16);
    dk[0] = a.v; dk[1] = bb.v;
  }
  stat_partial2(q, k, w4, ws + P_A1 + (size_t)blockIdx.x * 256, tid);
}

// redA: prep partials -> F_QSUM/F_KSUM. 32 blocks (4n x 8seg); 8 subs x 64 loads.
__global__ __launch_bounds__(256) void k_redA(float* __restrict__ ws) {
  const int tid = threadIdx.x;
  const int n = blockIdx.x >> 3, seg = blockIdx.x & 7;
  const int el = tid & 31, sub = tid >> 5;
  __shared__ float w[256];
  const float* src = ws + P_A1 + ((size_t)(n * 512 + sub * 64)) * 256 + seg * 32 + el;
  float a = 0.f;
#pragma unroll
  for (int i = 0; i < 64; ++i) a += src[(size_t)i * 256];
  w[tid] = a;
  __syncthreads();
  if (tid < 128) w[tid] += w[tid + 128];
  __syncthreads();
  if (tid < 64) w[tid] += w[tid + 64];
  __syncthreads();
  if (tid < 32) {
    const float v = w[tid] + w[tid + 32];
    const int elem = seg * 32 + tid;
    if (elem < 128) ws[F_QSUM + n * 128 + elem] = v;
    else ws[F_KSUM + n * 128 + (elem - 128)] = v;
  }
}

// Pass 2: qn = sum_l q*nr partials. 2048 blocks (8/CU); reads F_KSUM finals.
template <bool MIR>
__global__ __launch_bounds__(256) void k_refq(const float* __restrict__ Q,
                                              const unsigned short* __restrict__ sQ,
                                              float* __restrict__ ws) {
  const int tid = threadIdx.x;
  const int p = blockIdx.x * 256 + tid;
  const int n = blockIdx.x >> 9;
  __shared__ float ksE[128];
  __shared__ float w1[512];
  if (tid < 128) ksE[tid] = ws[F_KSUM + n * 128 + tid] + EPS;
  __syncthreads();
  const int h = tid & 7;
  float q[16];
  load_sig<MIR>(sQ, Q, p, q);
  float dr = 0.f;
#pragma unroll
  for (int d = 0; d < 16; ++d) dr += (q[d] + EPS) * ksE[h * 16 + d];
  const float nr = __fdividef(1.f, dr);
#pragma unroll
  for (int d = 0; d < 16; ++d) q[d] *= nr;
  stat_partial1(q, w1, ws + P_A2 + (size_t)blockIdx.x * 128, tid);
}

// redB: qn partials -> F_QN. 16 blocks (4n x 4seg).
__global__ __launch_bounds__(256) void k_redB(float* __restrict__ ws) {
  const int tid = threadIdx.x;
  const int n = blockIdx.x >> 2, seg = blockIdx.x & 3;
  const int el = tid & 31, sub = tid >> 5;
  __shared__ float w[256];
  const float* src = ws + P_A2 + ((size_t)(n * 512 + sub * 64)) * 128 + seg * 32 + el;
  float a = 0.f;
#pragma unroll
  for (int i = 0; i < 64; ++i) a += src[(size_t)i * 128];
  w[tid] = a;
  __syncthreads();
  if (tid < 128) w[tid] += w[tid + 128];
  __syncthreads();
  if (tid < 64) w[tid] += w[tid + 64];
  __syncthreads();
  if (tid < 32) ws[F_QN + n * 128 + seg * 32 + tid] = w[tid] + w[tid + 32];
}

// Pass 3: nc/kn, w = exp(k.qnE), ssum, weighted-KV tile partials.
// 2048 blocks x 1 tile of 32 rows; reads F_QSUM/F_QN finals; no atomics.
template <bool MIR>
__global__ __launch_bounds__(256) void k_kv(const float* __restrict__ K, const float* __restrict__ V,
                                            const unsigned short* __restrict__ sK,
                                            float* __restrict__ ws) {
  const int tid = threadIdx.x;
  const int blk = blockIdx.x;
  const int n = blk >> 9;
  constexpr int RS = 132;              // row stride: head-stride 16 (aligned wide reads), +4 pad
  __shared__ float qnE[128], qsE[128];
  __shared__ float ssb[8];
  __shared__ float w1[512];
  __shared__ __align__(16) float kwL[32 * RS];
  __shared__ __align__(16) float vL[32 * RS];
  if (tid < 128) {
    qnE[tid] = ws[F_QN + n * 128 + tid] + EPS;
    qsE[tid] = ws[F_QSUM + n * 128 + tid] + EPS;
  }
  if (tid < 8) ssb[tid] = 0.f;
  __syncthreads();
  const int h = tid & 7, ri = tid >> 3, lane = tid & 63;
  const int h2 = tid >> 5;
  const int d0 = ((tid >> 2) & 7) * 2;
  const int e0 = (tid & 3) * 4;
  const int p = blk * 256 + tid;
  float k[16], v[16];
  load_sig<MIR>(sK, K, p, k);
  load_raw16(V, p, v);
  float dc = 0.f, ncr = 0.f;
#pragma unroll
  for (int d = 0; d < 16; ++d) {
    const float ke = k[d] + EPS;
    dc += ke * qsE[h * 16 + d];
    ncr += ke * qnE[h * 16 + d];
  }
  const float nc = __fdividef(1.f, dc);
  float kn[16];
#pragma unroll
  for (int d = 0; d < 16; ++d) kn[d] = k[d] * nc;
  const float w = __expf(ncr);   // ncr is O(1): no max-subtraction needed
  float sw = hred(w);
  if (lane < 8) atomicAdd(&ssb[lane], sw);   // LDS atomic, 8 addresses
  const int wb = ri * RS + h * 16;
#pragma unroll
  for (int d = 0; d < 16; ++d) { kwL[wb + d] = k[d] * w; vL[wb + d] = v[d]; }
  __syncthreads();
  float acc[2][4] = {{0.f, 0.f, 0.f, 0.f}, {0.f, 0.f, 0.f, 0.f}};
  const int rb0 = h2 * 16;
#pragma unroll 4
  for (int r = 0; r < 32; ++r) {
    const int rb = r * RS + rb0;
    const float2 kk = *reinterpret_cast<const float2*>(&kwL[rb + d0]);
    const float4 vv = *reinterpret_cast<const float4*>(&vL[rb + e0]);
    acc[0][0] += kk.x * vv.x; acc[0][1] += kk.x * vv.y;
    acc[0][2] += kk.x * vv.z; acc[0][3] += kk.x * vv.w;
    acc[1][0] += kk.y * vv.x; acc[1][1] += kk.y * vv.y;
    acc[1][2] += kk.y * vv.z; acc[1][3] += kk.y * vv.w;
  }
  __syncthreads();
  // per-block partial writes (deterministic)
  stat_partial1(kn, w1, ws + P_KN + (size_t)blk * 128, tid);
  if (tid < 8) ws[P_SS + (size_t)blk * 8 + tid] = ssb[tid];
  float* pk = ws + P_KV + (size_t)blk * 2048;
  *reinterpret_cast<float4*>(pk + h2 * 256 + d0 * 16 + e0) =
      make_float4(acc[0][0], acc[0][1], acc[0][2], acc[0][3]);
  *reinterpret_cast<float4*>(pk + h2 * 256 + (d0 + 1) * 16 + e0) =
      make_float4(acc[1][0], acc[1][1], acc[1][2], acc[1][3]);
}

// redC: KV/kn/ssum partials -> finals. 276 blocks with role switch.
__global__ __launch_bounds__(256) void k_redC(float* __restrict__ ws) {
  const int tid = threadIdx.x;
  const int blk = blockIdx.x;
  __shared__ float w[256];
  if (blk < 256) {                     // KV: 4n x 64seg, 8 subs x 64 loads
    const int n = blk >> 6, seg = blk & 63;
    const int el = tid & 31, sub = tid >> 5;
    const float* src = ws + P_KV + ((size_t)(n * 512 + sub * 64)) * 2048 + seg * 32 + el;
    float a = 0.f;
#pragma unroll
    for (int i = 0; i < 64; ++i) a += src[(size_t)i * 2048];
    w[tid] = a;
    __syncthreads();
    if (tid < 128) w[tid] += w[tid + 128];
    __syncthreads();
    if (tid < 64) w[tid] += w[tid + 64];
    __syncthreads();
    if (tid < 32) ws[F_KV + n * 2048 + seg * 32 + tid] = w[tid] + w[tid + 32];
  } else if (blk < 272) {              // kn: 4n x 4seg
    const int b2 = blk - 256;
    const int n = b2 >> 2, seg = b2 & 3;
    const int el = tid & 31, sub = tid >> 5;
    const float* src = ws + P_KN + ((size_t)(n * 512 + sub * 64)) * 128 + seg * 32 + el;
    float a = 0.f;
#pragma unroll
    for (int i = 0; i < 64; ++i) a += src[(size_t)i * 128];
    w[tid] = a;
    __syncthreads();
    if (tid < 128) w[tid] += w[tid + 128];
    __syncthreads();
    if (tid < 64) w[tid] += w[tid + 64];
    __syncthreads();
    if (tid < 32) ws[F_KN + n * 128 + seg * 32 + tid] = w[tid] + w[tid + 32];
  } else {                             // ssum: 1 block per n
    const int n = blk - 272;
    const int h = tid & 7, sub = tid >> 3;   // 32 subs x 16 loads
    const float* src = ws + P_SS + ((size_t)(n * 512 + sub * 16)) * 8 + h;
    float a = 0.f;
#pragma unroll
    for (int i = 0; i < 16; ++i) a += src[(size_t)i * 8];
    w[tid] = a;
    __syncthreads();
    if (tid < 128) w[tid] += w[tid + 128];
    __syncthreads();
    if (tid < 64) w[tid] += w[tid + 64];
    __syncthreads();
    if (tid < 32) w[tid] += w[tid + 32];
    __syncthreads();
    if (tid < 16) w[tid] += w[tid + 16];
    __syncthreads();
    if (tid < 8) ws[F_SS + n * 8 + tid] = w[tid] + w[tid + 8];
  }
}

// Pass 4: x = q@kv * nr * nrr + v, LayerNorm, write out. Reads finals only.
template <bool MIR>
__global__ __launch_bounds__(256) void k_out(const float* __restrict__ Q, const float* __restrict__ V,
                                             const unsigned short* __restrict__ sQ,
                                             const float* __restrict__ gamma, const float* __restrict__ beta,
                                             const float* __restrict__ ws, float* __restrict__ out) {
  const int tid = threadIdx.x;
  const int p = blockIdx.x * 256 + tid;
  const int n = blockIdx.x >> 9;
  __shared__ __align__(16) float kvs[8 * 260];  // pad 260 → conflict-free by h
  __shared__ float ksE[128], knE[128], gm[16], bt[16], ssE[8];
  if (tid < 8) ssE[tid] = __fdividef((float)LL, ws[F_SS + n * 8 + tid]);
  if (tid >= 8 && tid < 136) {
    const int i = tid - 8;
    ksE[i] = ws[F_KSUM + n * 128 + i] + EPS;
    knE[i] = ws[F_KN + n * 128 + i] + EPS;
  }
  if (tid >= 136 && tid < 152) gm[tid - 136] = gamma[tid - 136];
  else if (tid >= 152 && tid < 168) bt[tid - 152] = beta[tid - 152];
  __syncthreads();
  for (int i = tid; i < 2048; i += 256) {
    const int hh = i >> 8, de = i & 255;
    kvs[hh * 260 + de] = ws[F_KV + n * 2048 + i] * ssE[hh];
  }
  __syncthreads();
  const int h = tid & 7;
  float q[16], v[16];
  load_sig<MIR>(sQ, Q, p, q);
  load_raw16(V, p, v);
  float dr = 0.f, drr = 0.f;
#pragma unroll
  for (int d = 0; d < 16; ++d) {
    const float qe = q[d] + EPS;
    dr += qe * ksE[h * 16 + d];
    drr += qe * knE[h * 16 + d];
  }
  const float sc = __fdividef(1.f, dr) * sigm(drr);
  float x[16];
#pragma unroll
  for (int e = 0; e < 16; ++e) x[e] = 0.f;
#pragma unroll
  for (int d = 0; d < 16; ++d) {
    const float qd = q[d];
    const float4* kr = reinterpret_cast<const float4*>(&kvs[h * 260 + d * 16]);
#pragma unroll
    for (int j = 0; j < 4; ++j) {
      float4 a = kr[j];
      x[4 * j] += qd * a.x; x[4 * j + 1] += qd * a.y;
      x[4 * j + 2] += qd * a.z; x[4 * j + 3] += qd * a.w;
    }
  }
#pragma unroll
  for (int e = 0; e < 16; ++e) x[e] = x[e] * sc + v[e];
  float mean = 0.f;
#pragma unroll
  for (int e = 0; e < 16; ++e) mean += x[e];
  mean *= (1.f / 16.f);
  float var = 0.f;
#pragma unroll
  for (int e = 0; e < 16; ++e) { const float t = x[e] - mean; var += t * t; }
  var *= (1.f / 16.f);
  const float inv = rsqrtf(var + LN_EPS);
#pragma unroll
  for (int e = 0; e < 16; ++e) x[e] = (x[e] - mean) * inv * gm[e] + bt[e];
  float4* op = reinterpret_cast<float4*>(out + (size_t)p * 16);
  op[0] = make_float4(x[0], x[1], x[2], x[3]);
  op[1] = make_float4(x[4], x[5], x[6], x[7]);
  op[2] = make_float4(x[8], x[9], x[10], x[11]);
  op[3] = make_float4(x[12], x[13], x[14], x[15]);
}

extern "C" void kernel_launch(void* const* d_in, const int* in_sizes, int n_in,
                              void* d_out, int out_size, void* d_ws, size_t ws_size,
                              hipStream_t stream) {
  const float* Q = (const float*)d_in[0];
  const float* K = (const float*)d_in[1];
  const float* V = (const float*)d_in[2];
  const float* gamma = (const float*)d_in[3];
  const float* beta = (const float*)d_in[4];
  float* ws = (float*)d_ws;
  float* out = (float*)d_out;
  unsigned short* sQ = (unsigned short*)((char*)d_ws + MIR_Q_BYTE);
  unsigned short* sK = (unsigned short*)((char*)d_ws + MIR_K_BYTE);

  const dim3 blk(256);
  const int gBig = NPAIR / 256;        // 2048 blocks (8/CU) for all streamers

  if (ws_size >= WS_FULL) {
    k_prep<true><<<gBig, blk, 0, stream>>>(Q, K, ws, sQ, sK);
    k_redA<<<32, blk, 0, stream>>>(ws);
    k_refq<true><<<gBig, blk, 0, stream>>>(Q, sQ, ws);
    k_redB<<<16, blk, 0, stream>>>(ws);
    k_kv<true><<<gBig, blk, 0, stream>>>(K, V, sK, ws);
    k_redC<<<276, blk, 0, stream>>>(ws);
    k_out<true><<<gBig, blk, 0, stream>>>(Q, V, sQ, gamma, beta, ws, out);
  } else {
    k_prep<false><<<gBig, blk, 0, stream>>>(Q, K, ws, nullptr, nullptr);
    k_redA<<<32, blk, 0, stream>>>(ws);
    k_refq<false><<<gBig, blk, 0, stream>>>(Q, nullptr, ws);
    k_redB<<<16, blk, 0, stream>>>(ws);
    k_kv<false><<<gBig, blk, 0, stream>>>(K, V, nullptr, ws);
    k_redC<<<276, blk, 0, stream>>>(ws);
    k_out<false><<<gBig, blk, 0, stream>>>(Q, V, nullptr, gamma, beta, ws, out);
  }
}